// Round 6
// baseline (87.335 us; speedup 1.0000x reference)
//
#include <hip/hip_runtime.h>
#include <hip/hip_cooperative_groups.h>

namespace cg = cooperative_groups;

// CantileverPINN: w, w_x, w_xx, w_xxx, w_xxxx for MLP 1->15->30->60->1 (tanh).
// Single cooperative kernel: phase 1 — blocks 0..255 build a 7-jet table
// (orders 0..6) at the 1024 cell centers (one wave per cell, lane-parallel
// neurons) while all other blocks prefetch x; grid sync; phase 2 — per-point
// Taylor eval from the owning cell center (channel k = sum_j o_{k+j} dx^j/j!).
// Worst truncation (channel 4): f^(7)*(h/2)^3/6 ~ 2e-11*f^(7) << 0.165.

#define M_CELLS 1024

static __device__ __forceinline__ float fast_tanh(float z) {
    float e = __builtin_amdgcn_exp2f(z * 2.88539008177792681472f); // 2*log2(e)
    return 1.0f - 2.0f * __builtin_amdgcn_rcpf(e + 1.0f);
}

// tanh 7-jet composition (Faa di Bruno orders 0..6).
#define TANH_JET7(z0, z1, z2, z3, z4, z5, z6, y0, y1, y2, y3, y4, y5, y6)    \
    {                                                                        \
        float t_ = fast_tanh(z0);                                            \
        float u_ = t_ * t_;                                                  \
        float s_ = 1.f - u_;                                                 \
        float g1 = s_;                                                       \
        float g2 = -2.f * t_ * s_;                                           \
        float g3 = s_ * (6.f * u_ - 2.f);                                    \
        float g4 = t_ * s_ * (16.f - 24.f * u_);                             \
        float g5 = s_ * (16.f + u_ * (-120.f + 120.f * u_));                 \
        float g6 = s_ * t_ * (-272.f + u_ * (960.f - 720.f * u_));           \
        float p2 = (z1) * (z1);                                              \
        float p4 = p2 * p2;                                                  \
        float p6 = p4 * p2;                                                  \
        y0 = t_;                                                             \
        y1 = g1 * (z1);                                                      \
        y2 = g2 * p2 + g1 * (z2);                                            \
        y3 = g3 * p2 * (z1) + 3.f * g2 * (z1) * (z2) + g1 * (z3);            \
        y4 = g4 * p4 + 6.f * g3 * p2 * (z2)                                  \
           + g2 * (4.f * (z1) * (z3) + 3.f * (z2) * (z2)) + g1 * (z4);       \
        y5 = g5 * p4 * (z1) + 10.f * g4 * p2 * (z1) * (z2)                   \
           + g3 * (10.f * p2 * (z3) + 15.f * (z1) * (z2) * (z2))             \
           + g2 * (5.f * (z1) * (z4) + 10.f * (z2) * (z3)) + g1 * (z5);      \
        y6 = g6 * p6                                                         \
           + g5 * (15.f * p4 * (z2))                                         \
           + g4 * (20.f * p2 * (z1) * (z3) + 45.f * p2 * (z2) * (z2))        \
           + g3 * (15.f * p2 * (z4) + 60.f * (z1) * (z2) * (z3)              \
                   + 15.f * (z2) * (z2) * (z2))                              \
           + g2 * (6.f * (z1) * (z5) + 15.f * (z2) * (z4)                    \
                   + 10.f * (z3) * (z3))                                     \
           + g1 * (z6);                                                      \
    }

// Taylor eval for one point from its cell-center record (orders 0..6).
static __device__ __forceinline__ void taylor_eval(
    const float4* __restrict__ tp, float xi, float* __restrict__ v)
{
    float u = xi * (float)M_CELLS;
    int i = (int)u;
    i = (i < 0) ? 0 : ((i >= M_CELLS) ? (M_CELLS - 1) : i);
    const float h = 1.0f / (float)M_CELLS;
    float dx = (u - (float)i - 0.5f) * h;

    float4 A = tp[i * 2];
    float4 B = tp[i * 2 + 1];
    float o0 = A.x, o1 = A.y, o2 = A.z, o3 = A.w;
    float o4 = B.x, o5 = B.y, o6 = B.z;

    float d2 = dx * 0.5f;
    float d3 = dx * (1.f / 3.f);
    float d4 = dx * 0.25f;
    float d5 = dx * 0.2f;
    float d6 = dx * (1.f / 6.f);

    v[0] = fmaf(dx, fmaf(d2, fmaf(d3, fmaf(d4, fmaf(d5, fmaf(d6, o6, o5), o4), o3), o2), o1), o0);
    v[1] = fmaf(dx, fmaf(d2, fmaf(d3, fmaf(d4, fmaf(d5, o6, o5), o4), o3), o2), o1);
    v[2] = fmaf(dx, fmaf(d2, fmaf(d3, fmaf(d4, o6, o5), o4), o3), o2);
    v[3] = fmaf(dx, fmaf(d2, fmaf(d3, o6, o5), o4), o3);
    v[4] = fmaf(dx, fmaf(d2, o6, o5), o4);
}

__global__ void __launch_bounds__(256) pinn_fused(
    const float* __restrict__ x,
    const float* __restrict__ W1, const float* __restrict__ b1,
    const float* __restrict__ W2, const float* __restrict__ b2,
    const float* __restrict__ W3, const float* __restrict__ b3,
    const float* __restrict__ W4, const float* __restrict__ b4,
    float* __restrict__ tab,
    float* __restrict__ out,
    int n)
{
    __shared__ float h1s[4][15 * 7];
    __shared__ float a2s[4][30 * 7];

    const int l  = threadIdx.x & 63;       // lane
    const int wv = threadIdx.x >> 6;       // wave in block (0..3)
    const int tid = blockIdx.x * 256 + threadIdx.x;
    const int idx4 = tid * 4;

    // ---- Prefetch x early: HBM latency hides under the table build ----
    float4 xv = make_float4(0.f, 0.f, 0.f, 0.f);
    const bool full = (idx4 + 3 < n);
    if (full) xv = *(const float4*)(x + idx4);

    // ---- Phase 1: blocks 0..255 build cells (wave w of block b -> cell 4b+w)
    if (blockIdx.x < (M_CELLS / 4)) {
        const int cell = blockIdx.x * 4 + wv;
        const float xi = ((float)cell + 0.5f) * (1.0f / (float)M_CELLS);

        // Layer 1: lane l<15 computes neuron l's 7-jet (z affine: z1=w)
        if (l < 15) {
            float w = W1[l];
            float z = fmaf(xi, w, b1[l]);
            float t = fast_tanh(z);
            float u = t * t;
            float s = 1.f - u;
            float g1 = s;
            float g2 = -2.f * t * s;
            float g3 = s * (6.f * u - 2.f);
            float g4 = t * s * (16.f - 24.f * u);
            float g5 = s * (16.f + u * (-120.f + 120.f * u));
            float g6 = s * t * (-272.f + u * (960.f - 720.f * u));
            float w2 = w * w;
            float w3 = w2 * w;
            h1s[wv][l * 7 + 0] = t;
            h1s[wv][l * 7 + 1] = g1 * w;
            h1s[wv][l * 7 + 2] = g2 * w2;
            h1s[wv][l * 7 + 3] = g3 * w3;
            h1s[wv][l * 7 + 4] = g4 * w2 * w2;
            h1s[wv][l * 7 + 5] = g5 * w2 * w3;
            h1s[wv][l * 7 + 6] = g6 * w3 * w3;
        }
        __syncthreads();

        // Layer 2: lane l<30 accumulates pre-act jet, then tanh jet
        if (l < 30) {
            float z0 = b2[l], z1 = 0.f, z2 = 0.f, z3 = 0.f, z4 = 0.f, z5 = 0.f, z6 = 0.f;
#pragma unroll
            for (int k = 0; k < 15; ++k) {
                float wv_ = W2[k * 30 + l];
                z0 = fmaf(wv_, h1s[wv][k * 7 + 0], z0);
                z1 = fmaf(wv_, h1s[wv][k * 7 + 1], z1);
                z2 = fmaf(wv_, h1s[wv][k * 7 + 2], z2);
                z3 = fmaf(wv_, h1s[wv][k * 7 + 3], z3);
                z4 = fmaf(wv_, h1s[wv][k * 7 + 4], z4);
                z5 = fmaf(wv_, h1s[wv][k * 7 + 5], z5);
                z6 = fmaf(wv_, h1s[wv][k * 7 + 6], z6);
            }
            float y0, y1, y2, y3, y4, y5, y6;
            TANH_JET7(z0, z1, z2, z3, z4, z5, z6, y0, y1, y2, y3, y4, y5, y6);
            a2s[wv][l * 7 + 0] = y0; a2s[wv][l * 7 + 1] = y1;
            a2s[wv][l * 7 + 2] = y2; a2s[wv][l * 7 + 3] = y3;
            a2s[wv][l * 7 + 4] = y4; a2s[wv][l * 7 + 5] = y5;
            a2s[wv][l * 7 + 6] = y6;
        }
        __syncthreads();

        // Layer 3 + output: lane l<60 computes neuron l, scaled by W4[l]
        float c0 = 0.f, c1 = 0.f, c2 = 0.f, c3 = 0.f, c4 = 0.f, c5 = 0.f, c6 = 0.f;
        if (l < 60) {
            float z0 = b3[l], z1 = 0.f, z2 = 0.f, z3 = 0.f, z4 = 0.f, z5 = 0.f, z6 = 0.f;
#pragma unroll
            for (int j = 0; j < 30; ++j) {
                float wv_ = W3[j * 60 + l];
                z0 = fmaf(wv_, a2s[wv][j * 7 + 0], z0);
                z1 = fmaf(wv_, a2s[wv][j * 7 + 1], z1);
                z2 = fmaf(wv_, a2s[wv][j * 7 + 2], z2);
                z3 = fmaf(wv_, a2s[wv][j * 7 + 3], z3);
                z4 = fmaf(wv_, a2s[wv][j * 7 + 4], z4);
                z5 = fmaf(wv_, a2s[wv][j * 7 + 5], z5);
                z6 = fmaf(wv_, a2s[wv][j * 7 + 6], z6);
            }
            float y0, y1, y2, y3, y4, y5, y6;
            TANH_JET7(z0, z1, z2, z3, z4, z5, z6, y0, y1, y2, y3, y4, y5, y6);
            float w4 = W4[l];
            c0 = w4 * y0; c1 = w4 * y1; c2 = w4 * y2; c3 = w4 * y3;
            c4 = w4 * y4; c5 = w4 * y5; c6 = w4 * y6;
        }

#pragma unroll
        for (int off = 32; off >= 1; off >>= 1) {
            c0 += __shfl_xor(c0, off);
            c1 += __shfl_xor(c1, off);
            c2 += __shfl_xor(c2, off);
            c3 += __shfl_xor(c3, off);
            c4 += __shfl_xor(c4, off);
            c5 += __shfl_xor(c5, off);
            c6 += __shfl_xor(c6, off);
        }

        if (l == 0) {
            float* tp = tab + cell * 8;
            tp[0] = c0 + b4[0];
            tp[1] = c1; tp[2] = c2; tp[3] = c3;
            tp[4] = c4; tp[5] = c5; tp[6] = c6; tp[7] = 0.f;
        }
        __threadfence();   // make tab stores device-visible before arrive
    }

    cg::this_grid().sync();

    // ---- Phase 2: Taylor eval, 4 points/thread ----
    const float4* tp = (const float4*)tab;
    if (full) {
        float vals[4][5];
        taylor_eval(tp, xv.x, vals[0]);
        taylor_eval(tp, xv.y, vals[1]);
        taylor_eval(tp, xv.z, vals[2]);
        taylor_eval(tp, xv.w, vals[3]);
#pragma unroll
        for (int k = 0; k < 5; ++k) {
            float4 o = make_float4(vals[0][k], vals[1][k], vals[2][k], vals[3][k]);
            *(float4*)(out + k * n + idx4) = o;
        }
    } else {
        for (int p = 0; p < 4 && idx4 + p < n; ++p) {
            float v[5];
            taylor_eval(tp, x[idx4 + p], v);
            for (int k = 0; k < 5; ++k) out[k * n + idx4 + p] = v[k];
        }
    }
}

extern "C" void kernel_launch(void* const* d_in, const int* in_sizes, int n_in,
                              void* d_out, int out_size, void* d_ws, size_t ws_size,
                              hipStream_t stream) {
    const float* x  = (const float*)d_in[0];
    const float* W1 = (const float*)d_in[1];
    const float* b1 = (const float*)d_in[2];
    const float* W2 = (const float*)d_in[3];
    const float* b2 = (const float*)d_in[4];
    const float* W3 = (const float*)d_in[5];
    const float* b3 = (const float*)d_in[6];
    const float* W4 = (const float*)d_in[7];
    const float* b4 = (const float*)d_in[8];
    float* out = (float*)d_out;
    int n = in_sizes[0];
    float* tab = (float*)d_ws;                 // M_CELLS*8 floats = 32KB

    int blocks = (n + 1023) / 1024;            // 4 pts/thread, 256 thr/block
    if (blocks < M_CELLS / 4) blocks = M_CELLS / 4;

    void* args[] = {(void*)&x, (void*)&W1, (void*)&b1, (void*)&W2, (void*)&b2,
                    (void*)&W3, (void*)&b3, (void*)&W4, (void*)&b4,
                    (void*)&tab, (void*)&out, (void*)&n};
    hipLaunchCooperativeKernel((const void*)pinn_fused, dim3(blocks), dim3(256),
                               args, 0, stream);
}

// Round 7
// 15.225 us; speedup vs baseline: 5.7362x; 5.7362x over previous
//
#include <hip/hip_runtime.h>

// CantileverPINN: w, w_x, w_xx, w_xxx, w_xxxx for MLP 1->15->30->60->1 (tanh).
// Two-kernel structure (cooperative fusion measured 4.6x WORSE — grid.sync
// across 8 XCDs costs ~60us; keep separate graph-captured dispatches):
//   1) build_table_wave: 7-jet (orders 0..6) at 1024 cell centers, one wave
//      per cell (4 waves/block), lane-parallel across neurons.
//   2) interp_points8: per-point Taylor eval from owning cell center,
//      channel k = sum_j o_{k+j} dx^j / j!, dx in [-h/2,h/2]. Worst-case
//      truncation (channel 4): f^(7)*(h/2)^3/6 ~ 2e-11*f^(7) << 0.165.
// 8 points/thread, one 32B L1-resident record per point.

#define M_CELLS 1024

static __device__ __forceinline__ float fast_tanh(float z) {
    float e = __builtin_amdgcn_exp2f(z * 2.88539008177792681472f); // 2*log2(e)
    return 1.0f - 2.0f * __builtin_amdgcn_rcpf(e + 1.0f);
}

// tanh 7-jet composition (Faa di Bruno orders 0..6).
#define TANH_JET7(z0, z1, z2, z3, z4, z5, z6, y0, y1, y2, y3, y4, y5, y6)    \
    {                                                                        \
        float t_ = fast_tanh(z0);                                            \
        float u_ = t_ * t_;                                                  \
        float s_ = 1.f - u_;                                                 \
        float g1 = s_;                                                       \
        float g2 = -2.f * t_ * s_;                                           \
        float g3 = s_ * (6.f * u_ - 2.f);                                    \
        float g4 = t_ * s_ * (16.f - 24.f * u_);                             \
        float g5 = s_ * (16.f + u_ * (-120.f + 120.f * u_));                 \
        float g6 = s_ * t_ * (-272.f + u_ * (960.f - 720.f * u_));           \
        float p2 = (z1) * (z1);                                              \
        float p4 = p2 * p2;                                                  \
        float p6 = p4 * p2;                                                  \
        y0 = t_;                                                             \
        y1 = g1 * (z1);                                                      \
        y2 = g2 * p2 + g1 * (z2);                                            \
        y3 = g3 * p2 * (z1) + 3.f * g2 * (z1) * (z2) + g1 * (z3);            \
        y4 = g4 * p4 + 6.f * g3 * p2 * (z2)                                  \
           + g2 * (4.f * (z1) * (z3) + 3.f * (z2) * (z2)) + g1 * (z4);       \
        y5 = g5 * p4 * (z1) + 10.f * g4 * p2 * (z1) * (z2)                   \
           + g3 * (10.f * p2 * (z3) + 15.f * (z1) * (z2) * (z2))             \
           + g2 * (5.f * (z1) * (z4) + 10.f * (z2) * (z3)) + g1 * (z5);      \
        y6 = g6 * p6                                                         \
           + g5 * (15.f * p4 * (z2))                                         \
           + g4 * (20.f * p2 * (z1) * (z3) + 45.f * p2 * (z2) * (z2))        \
           + g3 * (15.f * p2 * (z4) + 60.f * (z1) * (z2) * (z3)              \
                   + 15.f * (z2) * (z2) * (z2))                              \
           + g2 * (6.f * (z1) * (z5) + 15.f * (z2) * (z4)                    \
                   + 10.f * (z3) * (z3))                                     \
           + g1 * (z6);                                                      \
    }

// 4 waves per block; wave wv builds cell = blockIdx.x*4 + wv at its center.
__global__ void __launch_bounds__(256) build_table_wave(
    const float* __restrict__ W1, const float* __restrict__ b1,
    const float* __restrict__ W2, const float* __restrict__ b2,
    const float* __restrict__ W3, const float* __restrict__ b3,
    const float* __restrict__ W4, const float* __restrict__ b4,
    float* __restrict__ tab)
{
    __shared__ float h1s[4][15 * 7];
    __shared__ float a2s[4][30 * 7];

    const int l  = threadIdx.x & 63;
    const int wv = threadIdx.x >> 6;
    const int cell = blockIdx.x * 4 + wv;
    const float xi = ((float)cell + 0.5f) * (1.0f / (float)M_CELLS);

    // ---- Layer 1: lane l<15 computes neuron l's 7-jet (z affine: z1=w) ----
    if (l < 15) {
        float w = W1[l];
        float z = fmaf(xi, w, b1[l]);
        float t = fast_tanh(z);
        float u = t * t;
        float s = 1.f - u;
        float g1 = s;
        float g2 = -2.f * t * s;
        float g3 = s * (6.f * u - 2.f);
        float g4 = t * s * (16.f - 24.f * u);
        float g5 = s * (16.f + u * (-120.f + 120.f * u));
        float g6 = s * t * (-272.f + u * (960.f - 720.f * u));
        float w2 = w * w;
        float w3 = w2 * w;
        h1s[wv][l * 7 + 0] = t;
        h1s[wv][l * 7 + 1] = g1 * w;
        h1s[wv][l * 7 + 2] = g2 * w2;
        h1s[wv][l * 7 + 3] = g3 * w3;
        h1s[wv][l * 7 + 4] = g4 * w2 * w2;
        h1s[wv][l * 7 + 5] = g5 * w2 * w3;
        h1s[wv][l * 7 + 6] = g6 * w3 * w3;
    }
    __syncthreads();

    // ---- Layer 2: lane l<30 accumulates pre-act jet, then tanh jet ----
    if (l < 30) {
        float z0 = b2[l], z1 = 0.f, z2 = 0.f, z3 = 0.f, z4 = 0.f, z5 = 0.f, z6 = 0.f;
#pragma unroll
        for (int k = 0; k < 15; ++k) {
            float wk = W2[k * 30 + l];               // coalesced across lanes
            z0 = fmaf(wk, h1s[wv][k * 7 + 0], z0);   // broadcast LDS reads
            z1 = fmaf(wk, h1s[wv][k * 7 + 1], z1);
            z2 = fmaf(wk, h1s[wv][k * 7 + 2], z2);
            z3 = fmaf(wk, h1s[wv][k * 7 + 3], z3);
            z4 = fmaf(wk, h1s[wv][k * 7 + 4], z4);
            z5 = fmaf(wk, h1s[wv][k * 7 + 5], z5);
            z6 = fmaf(wk, h1s[wv][k * 7 + 6], z6);
        }
        float y0, y1, y2, y3, y4, y5, y6;
        TANH_JET7(z0, z1, z2, z3, z4, z5, z6, y0, y1, y2, y3, y4, y5, y6);
        a2s[wv][l * 7 + 0] = y0; a2s[wv][l * 7 + 1] = y1;
        a2s[wv][l * 7 + 2] = y2; a2s[wv][l * 7 + 3] = y3;
        a2s[wv][l * 7 + 4] = y4; a2s[wv][l * 7 + 5] = y5;
        a2s[wv][l * 7 + 6] = y6;
    }
    __syncthreads();

    // ---- Layer 3 + output: lane l<60 computes neuron l, scaled by W4[l] ----
    float c0 = 0.f, c1 = 0.f, c2 = 0.f, c3 = 0.f, c4 = 0.f, c5 = 0.f, c6 = 0.f;
    if (l < 60) {
        float z0 = b3[l], z1 = 0.f, z2 = 0.f, z3 = 0.f, z4 = 0.f, z5 = 0.f, z6 = 0.f;
#pragma unroll
        for (int j = 0; j < 30; ++j) {
            float wj = W3[j * 60 + l];               // coalesced across lanes
            z0 = fmaf(wj, a2s[wv][j * 7 + 0], z0);
            z1 = fmaf(wj, a2s[wv][j * 7 + 1], z1);
            z2 = fmaf(wj, a2s[wv][j * 7 + 2], z2);
            z3 = fmaf(wj, a2s[wv][j * 7 + 3], z3);
            z4 = fmaf(wj, a2s[wv][j * 7 + 4], z4);
            z5 = fmaf(wj, a2s[wv][j * 7 + 5], z5);
            z6 = fmaf(wj, a2s[wv][j * 7 + 6], z6);
        }
        float y0, y1, y2, y3, y4, y5, y6;
        TANH_JET7(z0, z1, z2, z3, z4, z5, z6, y0, y1, y2, y3, y4, y5, y6);
        float w4 = W4[l];
        c0 = w4 * y0; c1 = w4 * y1; c2 = w4 * y2; c3 = w4 * y3;
        c4 = w4 * y4; c5 = w4 * y5; c6 = w4 * y6;
    }

    // ---- Wave reduction (60 active contributors) ----
#pragma unroll
    for (int off = 32; off >= 1; off >>= 1) {
        c0 += __shfl_xor(c0, off);
        c1 += __shfl_xor(c1, off);
        c2 += __shfl_xor(c2, off);
        c3 += __shfl_xor(c3, off);
        c4 += __shfl_xor(c4, off);
        c5 += __shfl_xor(c5, off);
        c6 += __shfl_xor(c6, off);
    }

    if (l == 0) {
        float* tp = tab + cell * 8;
        tp[0] = c0 + b4[0];
        tp[1] = c1; tp[2] = c2; tp[3] = c3;
        tp[4] = c4; tp[5] = c5; tp[6] = c6; tp[7] = 0.f;
    }
}

// Taylor eval for one point from its cell-center record (orders 0..6).
static __device__ __forceinline__ void taylor_eval(
    const float4* __restrict__ tp, float xi, float* __restrict__ v)
{
    float u = xi * (float)M_CELLS;
    int i = (int)u;
    i = (i < 0) ? 0 : ((i >= M_CELLS) ? (M_CELLS - 1) : i);
    const float h = 1.0f / (float)M_CELLS;
    float dx = (u - (float)i - 0.5f) * h;

    float4 A = tp[i * 2];
    float4 B = tp[i * 2 + 1];
    float o0 = A.x, o1 = A.y, o2 = A.z, o3 = A.w;
    float o4 = B.x, o5 = B.y, o6 = B.z;

    float d2 = dx * 0.5f;
    float d3 = dx * (1.f / 3.f);
    float d4 = dx * 0.25f;
    float d5 = dx * 0.2f;
    float d6 = dx * (1.f / 6.f);

    v[0] = fmaf(dx, fmaf(d2, fmaf(d3, fmaf(d4, fmaf(d5, fmaf(d6, o6, o5), o4), o3), o2), o1), o0);
    v[1] = fmaf(dx, fmaf(d2, fmaf(d3, fmaf(d4, fmaf(d5, o6, o5), o4), o3), o2), o1);
    v[2] = fmaf(dx, fmaf(d2, fmaf(d3, fmaf(d4, o6, o5), o4), o3), o2);
    v[3] = fmaf(dx, fmaf(d2, fmaf(d3, o6, o5), o4), o3);
    v[4] = fmaf(dx, fmaf(d2, o6, o5), o4);
}

// 8 points per thread: 2x float4 in, 10x float4 out, 32B record per point.
__global__ void __launch_bounds__(256) interp_points8(
    const float* __restrict__ x,
    const float* __restrict__ tab,
    float* __restrict__ out,
    int n)
{
    int tid = blockIdx.x * 256 + threadIdx.x;
    int idx8 = tid * 8;
    if (idx8 >= n) return;

    const float4* tp = (const float4*)tab;

    if (idx8 + 7 < n) {
        float4 xa = *(const float4*)(x + idx8);
        float4 xb = *(const float4*)(x + idx8 + 4);
        float vals[8][5];
        taylor_eval(tp, xa.x, vals[0]);
        taylor_eval(tp, xa.y, vals[1]);
        taylor_eval(tp, xa.z, vals[2]);
        taylor_eval(tp, xa.w, vals[3]);
        taylor_eval(tp, xb.x, vals[4]);
        taylor_eval(tp, xb.y, vals[5]);
        taylor_eval(tp, xb.z, vals[6]);
        taylor_eval(tp, xb.w, vals[7]);
#pragma unroll
        for (int k = 0; k < 5; ++k) {
            float4 oa = make_float4(vals[0][k], vals[1][k], vals[2][k], vals[3][k]);
            float4 ob = make_float4(vals[4][k], vals[5][k], vals[6][k], vals[7][k]);
            *(float4*)(out + k * n + idx8)     = oa;
            *(float4*)(out + k * n + idx8 + 4) = ob;
        }
    } else {
        for (int p = 0; p < 8 && idx8 + p < n; ++p) {
            float v[5];
            taylor_eval(tp, x[idx8 + p], v);
            for (int k = 0; k < 5; ++k) out[k * n + idx8 + p] = v[k];
        }
    }
}

extern "C" void kernel_launch(void* const* d_in, const int* in_sizes, int n_in,
                              void* d_out, int out_size, void* d_ws, size_t ws_size,
                              hipStream_t stream) {
    const float* x  = (const float*)d_in[0];
    const float* W1 = (const float*)d_in[1];
    const float* b1 = (const float*)d_in[2];
    const float* W2 = (const float*)d_in[3];
    const float* b2 = (const float*)d_in[4];
    const float* W3 = (const float*)d_in[5];
    const float* b3 = (const float*)d_in[6];
    const float* W4 = (const float*)d_in[7];
    const float* b4 = (const float*)d_in[8];
    float* out = (float*)d_out;
    int n = in_sizes[0];

    float* tab = (float*)d_ws;                 // M_CELLS*8 floats = 32KB

    build_table_wave<<<dim3(M_CELLS / 4), dim3(256), 0, stream>>>(
        W1, b1, W2, b2, W3, b3, W4, b4, tab);
    int threads = (n + 7) / 8;
    interp_points8<<<dim3((threads + 255) / 256), dim3(256), 0, stream>>>(
        x, tab, out, n);
}

// Round 8
// 14.626 us; speedup vs baseline: 5.9711x; 1.0410x over previous
//
#include <hip/hip_runtime.h>

// CantileverPINN: w, w_x, w_xx, w_xxx, w_xxxx for MLP 1->15->30->60->1 (tanh).
// Structure: the MLP input is SCALAR x in [0,1). Build a table of 7-jets
// (orders 0..6) at the 1024 CELL CENTERS — one WAVE per cell, lane-parallel
// across neurons — then per-point Taylor evaluation from the owning cell's
// center: channel k = sum_j o_{k+j} dx^j / j!, dx in [-h/2, h/2].
// Worst-case truncation (channel 4, 3 terms): f^(7)*(h/2)^3/6 ~ 2e-11*f^(7).
// One 32B record per point (L1-resident 32KB table), 4 points/thread.
//
// Measured config notes (MI355X):
//  - R5 config (this file): 14.3 us total; best measured.
//  - Cooperative single-kernel fusion (R6): 87 us — grid.sync over 8 XCDs
//    costs ~60 us. Never fuse via cooperative launch here.
//  - 256x256 builder + 8 pts/thread interp (R7): 15.2 us — neutral/worse.
//  - Both kernels are ~4-5 us combined; the rest is graph/dispatch overhead.

#define M_CELLS 1024

static __device__ __forceinline__ float fast_tanh(float z) {
    float e = __builtin_amdgcn_exp2f(z * 2.88539008177792681472f); // 2*log2(e)
    return 1.0f - 2.0f * __builtin_amdgcn_rcpf(e + 1.0f);
}

// tanh 7-jet composition (Faa di Bruno orders 0..6).
// g1=s, g2=-2ts, g3=s(6t^2-2), g4=ts(16-24t^2), g5=s(16-120t^2+120t^4),
// g6=st(-272+960t^2-720t^4), s=1-t^2.
#define TANH_JET7(z0, z1, z2, z3, z4, z5, z6, y0, y1, y2, y3, y4, y5, y6)    \
    {                                                                        \
        float t_ = fast_tanh(z0);                                            \
        float u_ = t_ * t_;                                                  \
        float s_ = 1.f - u_;                                                 \
        float g1 = s_;                                                       \
        float g2 = -2.f * t_ * s_;                                           \
        float g3 = s_ * (6.f * u_ - 2.f);                                    \
        float g4 = t_ * s_ * (16.f - 24.f * u_);                             \
        float g5 = s_ * (16.f + u_ * (-120.f + 120.f * u_));                 \
        float g6 = s_ * t_ * (-272.f + u_ * (960.f - 720.f * u_));           \
        float p2 = (z1) * (z1);                                              \
        float p4 = p2 * p2;                                                  \
        float p6 = p4 * p2;                                                  \
        y0 = t_;                                                             \
        y1 = g1 * (z1);                                                      \
        y2 = g2 * p2 + g1 * (z2);                                            \
        y3 = g3 * p2 * (z1) + 3.f * g2 * (z1) * (z2) + g1 * (z3);            \
        y4 = g4 * p4 + 6.f * g3 * p2 * (z2)                                  \
           + g2 * (4.f * (z1) * (z3) + 3.f * (z2) * (z2)) + g1 * (z4);       \
        y5 = g5 * p4 * (z1) + 10.f * g4 * p2 * (z1) * (z2)                   \
           + g3 * (10.f * p2 * (z3) + 15.f * (z1) * (z2) * (z2))             \
           + g2 * (5.f * (z1) * (z4) + 10.f * (z2) * (z3)) + g1 * (z5);      \
        y6 = g6 * p6                                                         \
           + g5 * (15.f * p4 * (z2))                                         \
           + g4 * (20.f * p2 * (z1) * (z3) + 45.f * p2 * (z2) * (z2))        \
           + g3 * (15.f * p2 * (z4) + 60.f * (z1) * (z2) * (z3)              \
                   + 15.f * (z2) * (z2) * (z2))                              \
           + g2 * (6.f * (z1) * (z5) + 15.f * (z2) * (z4)                    \
                   + 10.f * (z3) * (z3))                                     \
           + g1 * (z6);                                                      \
    }

// One wave (64 lanes) per cell; evaluate the 7-jet at the cell center.
__global__ void __launch_bounds__(64) build_table_wave(
    const float* __restrict__ W1, const float* __restrict__ b1,
    const float* __restrict__ W2, const float* __restrict__ b2,
    const float* __restrict__ W3, const float* __restrict__ b3,
    const float* __restrict__ W4, const float* __restrict__ b4,
    float* __restrict__ tab)
{
    __shared__ float h1s[15 * 7];
    __shared__ float a2s[30 * 7];

    int cell = blockIdx.x;
    int l = threadIdx.x;
    float xi = ((float)cell + 0.5f) * (1.0f / (float)M_CELLS);

    // ---- Layer 1: lane l<15 computes neuron l's 7-jet (z affine: z1=w) ----
    if (l < 15) {
        float w = W1[l];
        float z = fmaf(xi, w, b1[l]);
        float t = fast_tanh(z);
        float u = t * t;
        float s = 1.f - u;
        float g1 = s;
        float g2 = -2.f * t * s;
        float g3 = s * (6.f * u - 2.f);
        float g4 = t * s * (16.f - 24.f * u);
        float g5 = s * (16.f + u * (-120.f + 120.f * u));
        float g6 = s * t * (-272.f + u * (960.f - 720.f * u));
        float w2 = w * w;
        float w3 = w2 * w;
        h1s[l * 7 + 0] = t;
        h1s[l * 7 + 1] = g1 * w;
        h1s[l * 7 + 2] = g2 * w2;
        h1s[l * 7 + 3] = g3 * w3;
        h1s[l * 7 + 4] = g4 * w2 * w2;
        h1s[l * 7 + 5] = g5 * w2 * w3;
        h1s[l * 7 + 6] = g6 * w3 * w3;
    }
    __syncthreads();

    // ---- Layer 2: lane l<30 accumulates pre-act jet, then tanh jet ----
    if (l < 30) {
        float z0 = b2[l], z1 = 0.f, z2 = 0.f, z3 = 0.f, z4 = 0.f, z5 = 0.f, z6 = 0.f;
#pragma unroll
        for (int k = 0; k < 15; ++k) {
            float wv = W2[k * 30 + l];               // coalesced across lanes
            z0 = fmaf(wv, h1s[k * 7 + 0], z0);       // broadcast LDS reads
            z1 = fmaf(wv, h1s[k * 7 + 1], z1);
            z2 = fmaf(wv, h1s[k * 7 + 2], z2);
            z3 = fmaf(wv, h1s[k * 7 + 3], z3);
            z4 = fmaf(wv, h1s[k * 7 + 4], z4);
            z5 = fmaf(wv, h1s[k * 7 + 5], z5);
            z6 = fmaf(wv, h1s[k * 7 + 6], z6);
        }
        float y0, y1, y2, y3, y4, y5, y6;
        TANH_JET7(z0, z1, z2, z3, z4, z5, z6, y0, y1, y2, y3, y4, y5, y6);
        a2s[l * 7 + 0] = y0; a2s[l * 7 + 1] = y1; a2s[l * 7 + 2] = y2;
        a2s[l * 7 + 3] = y3; a2s[l * 7 + 4] = y4; a2s[l * 7 + 5] = y5;
        a2s[l * 7 + 6] = y6;
    }
    __syncthreads();

    // ---- Layer 3 + output: lane l<60 computes neuron l, scales by W4[l] ----
    float c0 = 0.f, c1 = 0.f, c2 = 0.f, c3 = 0.f, c4 = 0.f, c5 = 0.f, c6 = 0.f;
    if (l < 60) {
        float z0 = b3[l], z1 = 0.f, z2 = 0.f, z3 = 0.f, z4 = 0.f, z5 = 0.f, z6 = 0.f;
#pragma unroll
        for (int j = 0; j < 30; ++j) {
            float wv = W3[j * 60 + l];               // coalesced across lanes
            z0 = fmaf(wv, a2s[j * 7 + 0], z0);
            z1 = fmaf(wv, a2s[j * 7 + 1], z1);
            z2 = fmaf(wv, a2s[j * 7 + 2], z2);
            z3 = fmaf(wv, a2s[j * 7 + 3], z3);
            z4 = fmaf(wv, a2s[j * 7 + 4], z4);
            z5 = fmaf(wv, a2s[j * 7 + 5], z5);
            z6 = fmaf(wv, a2s[j * 7 + 6], z6);
        }
        float y0, y1, y2, y3, y4, y5, y6;
        TANH_JET7(z0, z1, z2, z3, z4, z5, z6, y0, y1, y2, y3, y4, y5, y6);
        float w4 = W4[l];
        c0 = w4 * y0; c1 = w4 * y1; c2 = w4 * y2; c3 = w4 * y3;
        c4 = w4 * y4; c5 = w4 * y5; c6 = w4 * y6;
    }

    // ---- Wave reduction over 64 lanes (60 active contributors) ----
#pragma unroll
    for (int off = 32; off >= 1; off >>= 1) {
        c0 += __shfl_xor(c0, off);
        c1 += __shfl_xor(c1, off);
        c2 += __shfl_xor(c2, off);
        c3 += __shfl_xor(c3, off);
        c4 += __shfl_xor(c4, off);
        c5 += __shfl_xor(c5, off);
        c6 += __shfl_xor(c6, off);
    }

    if (l == 0) {
        float* tp = tab + cell * 8;
        tp[0] = c0 + b4[0];
        tp[1] = c1; tp[2] = c2; tp[3] = c3;
        tp[4] = c4; tp[5] = c5; tp[6] = c6; tp[7] = 0.f;
    }
}

// Taylor eval for one point from its cell-center record (orders 0..6).
static __device__ __forceinline__ void taylor_eval(
    const float4* __restrict__ tp, float xi, float* __restrict__ v)
{
    float u = xi * (float)M_CELLS;
    int i = (int)u;
    i = (i < 0) ? 0 : ((i >= M_CELLS) ? (M_CELLS - 1) : i);
    const float h = 1.0f / (float)M_CELLS;
    float dx = (u - (float)i - 0.5f) * h;

    float4 A = tp[i * 2];
    float4 B = tp[i * 2 + 1];
    float o0 = A.x, o1 = A.y, o2 = A.z, o3 = A.w;
    float o4 = B.x, o5 = B.y, o6 = B.z;

    float d2 = dx * 0.5f;
    float d3 = dx * (1.f / 3.f);
    float d4 = dx * 0.25f;
    float d5 = dx * 0.2f;
    float d6 = dx * (1.f / 6.f);

    v[0] = fmaf(dx, fmaf(d2, fmaf(d3, fmaf(d4, fmaf(d5, fmaf(d6, o6, o5), o4), o3), o2), o1), o0);
    v[1] = fmaf(dx, fmaf(d2, fmaf(d3, fmaf(d4, fmaf(d5, o6, o5), o4), o3), o2), o1);
    v[2] = fmaf(dx, fmaf(d2, fmaf(d3, fmaf(d4, o6, o5), o4), o3), o2);
    v[3] = fmaf(dx, fmaf(d2, fmaf(d3, o6, o5), o4), o3);
    v[4] = fmaf(dx, fmaf(d2, o6, o5), o4);
}

// 4 points per thread, float4 in / 5x float4 out, one 32B record per point.
__global__ void __launch_bounds__(256) interp_points4(
    const float* __restrict__ x,
    const float* __restrict__ tab,
    float* __restrict__ out,
    int n)
{
    int tid = blockIdx.x * 256 + threadIdx.x;
    int idx4 = tid * 4;
    if (idx4 >= n) return;

    const float4* tp = (const float4*)tab;
    float vals[4][5];

    if (idx4 + 3 < n) {
        float4 xv = *(const float4*)(x + idx4);
        taylor_eval(tp, xv.x, vals[0]);
        taylor_eval(tp, xv.y, vals[1]);
        taylor_eval(tp, xv.z, vals[2]);
        taylor_eval(tp, xv.w, vals[3]);
#pragma unroll
        for (int k = 0; k < 5; ++k) {
            float4 o = make_float4(vals[0][k], vals[1][k], vals[2][k], vals[3][k]);
            *(float4*)(out + k * n + idx4) = o;
        }
    } else {
        for (int p = 0; p < 4 && idx4 + p < n; ++p) {
            float v[5];
            taylor_eval(tp, x[idx4 + p], v);
            for (int k = 0; k < 5; ++k) out[k * n + idx4 + p] = v[k];
        }
    }
}

extern "C" void kernel_launch(void* const* d_in, const int* in_sizes, int n_in,
                              void* d_out, int out_size, void* d_ws, size_t ws_size,
                              hipStream_t stream) {
    const float* x  = (const float*)d_in[0];
    const float* W1 = (const float*)d_in[1];
    const float* b1 = (const float*)d_in[2];
    const float* W2 = (const float*)d_in[3];
    const float* b2 = (const float*)d_in[4];
    const float* W3 = (const float*)d_in[5];
    const float* b3 = (const float*)d_in[6];
    const float* W4 = (const float*)d_in[7];
    const float* b4 = (const float*)d_in[8];
    float* out = (float*)d_out;
    int n = in_sizes[0];

    float* tab = (float*)d_ws;                 // M_CELLS*8 floats = 32KB

    build_table_wave<<<dim3(M_CELLS), dim3(64), 0, stream>>>(
        W1, b1, W2, b2, W3, b3, W4, b4, tab);
    int threads = (n + 3) / 4;
    interp_points4<<<dim3((threads + 255) / 256), dim3(256), 0, stream>>>(
        x, tab, out, n);
}